// Round 5
// baseline (141.379 us; speedup 1.0000x reference)
//
#include <hip/hip_runtime.h>

// FlowGNN: 2-layer temporal GNN, fused single kernel.
// N=100000, D=32, B=2048, F_IN=64, F_H=128, F_OUT=64.
// R4 = R3 resubmitted (GPU timeout last round; kernel still unmeasured).
// R3: latency-hiding restructure. R1/R2 both hit a 51us wall with L3-resident
// data -> latency x occupancy bound, not BW/MLP. Changes:
//  (a) all frontier metadata (idx rows + temporal masks) pre-staged in LDS
//      cooperatively -> removes ~600cy dependent load from each j's chain;
//  (b) gather issues 2 rows/instruction (float2, lane-halves) and overlaps
//      with the PREVIOUS j's GEMM1 (software pipeline);
//  (c) LDS union (red/aggm overlay W0s) keeps 39.5KB -> 4 blocks/CU capacity.
#define DEG   32
#define F_IN  64
#define F_H   128
#define F_OUT 64
#define NW    8
#define BLOCK (NW * 64)

__launch_bounds__(BLOCK, 6)   // cap VGPR at 85; est. usage ~70
__global__ void flowgnn_kernel(const float* __restrict__ x,
                               const float* __restrict__ times,
                               const float* __restrict__ ts,
                               const float* __restrict__ W0,
                               const float* __restrict__ b0,
                               const float* __restrict__ W1,
                               const float* __restrict__ b1,
                               const int*   __restrict__ batch,
                               const int*   __restrict__ idx,
                               float*       __restrict__ out)
{
    // ---- LDS pool with phase overlays (39472 B total -> 4 blocks/CU) ----
    __shared__ __align__(16) float smem[9868];
    float*    W0s     = smem;                       // [8192]  phase 1 only
    int*      idx_s   = (int*)(smem + 8192);        // [33*32] neighbor ids
    float*    t2_s    = smem + 9248;                // [33]    frontier query times
    int*      nodes_s = (int*)(smem + 9284);        // [33]    frontier node ids
    unsigned* mask_s  = (unsigned*)(smem + 9320);   // [33]    temporal masks (bit d)
    float*    meanw   = smem + 9356;                // [NW*64] per-wave mean broadcast
    // phase 2 (after barrier): red = smem[0..1024), aggm = smem[1024..1152)

    const int b    = blockIdx.x;
    const int t    = threadIdx.x;
    const int wid  = t >> 6;
    const int lane = t & 63;
    const int l32  = lane & 31;
    const int hsel = (lane >> 5) << 4;     // 0 for lanes<32, 16 for lanes>=32

    const int   node0 = batch[b];
    const float tb    = times[b];
    const float2* __restrict__ x2 = (const float2*)x;

    // ---- frontier ids/times ----
    if (t < DEG) {
        t2_s[t]    = ts [node0 * DEG + t];
        nodes_s[t] = idx[node0 * DEG + t];
    }
    if (t == DEG) { t2_s[DEG] = tb; nodes_s[DEG] = node0; }
    __syncthreads();

    // ---- stage W0 (coalesced float4) + all frontier metadata ----
    {
        const float4* src = (const float4*)W0;
        float4*       dst = (float4*)W0s;
        #pragma unroll
        for (int i = t; i < (F_IN * F_H) / 4; i += BLOCK) dst[i] = src[i];
    }
    #pragma unroll
    for (int q = 0; q < 3; ++q) {
        const int p = t + q * BLOCK;           // pair index -> (j = p>>5, d = p&31)
        bool bit = false;
        if (p < (DEG + 1) * DEG) {
            const int j = p >> 5, d = p & 31;
            const int nd = nodes_s[j];
            idx_s[p] = idx[nd * DEG + d];
            bit = (ts[nd * DEG + d] <= t2_s[j]);
        }
        const unsigned long long bal = __ballot(bit);   // wave covers 2 aligned rows
        const int prow = (q * BLOCK + (t & ~63)) >> 5;
        if (p < (DEG + 1) * DEG) {
            if (lane == 0)  mask_s[prow]     = (unsigned)(bal & 0xffffffffULL);
            if (lane == 32) mask_s[prow + 1] = (unsigned)(bal >> 32);
        }
    }
    __syncthreads();

    // wave-uniform live-frontier bitmap (bits 0..32)
    const unsigned long long liveM =
        __ballot((lane <= DEG) ? (t2_s[lane] <= tb) : false);

    const float b0x = b0[2 * lane];
    const float b0y = b0[2 * lane + 1];
    float a1x = 0.f, a1y = 0.f;
    int jprev = -1;

    // GEMM1 for the previously-consumed j (mean already in meanw[wid])
    auto do_gemm1 = [&]() {
        float hx = 0.f, hy = 0.f;
        #pragma unroll
        for (int f4 = 0; f4 < F_IN / 4; ++f4) {
            const float4 m4 = *(const float4*)&meanw[wid * F_IN + 4 * f4];
            const float2 wa = *(const float2*)&W0s[(4 * f4 + 0) * F_H + 2 * lane];
            const float2 wb = *(const float2*)&W0s[(4 * f4 + 1) * F_H + 2 * lane];
            const float2 wc = *(const float2*)&W0s[(4 * f4 + 2) * F_H + 2 * lane];
            const float2 wd = *(const float2*)&W0s[(4 * f4 + 3) * F_H + 2 * lane];
            hx += m4.x * wa.x; hy += m4.x * wa.y;
            hx += m4.y * wb.x; hy += m4.y * wb.y;
            hx += m4.z * wc.x; hy += m4.z * wc.y;
            hx += m4.w * wd.x; hy += m4.w * wd.y;
        }
        a1x += fmaxf(hx + b0x, 0.f);
        a1y += fmaxf(hy + b0y, 0.f);
    };

    // ---- main loop: waves own j = wid, wid+NW, ...; pipeline gather vs GEMM ----
    for (int j = wid; j <= DEG; j += NW) {
        if (!((liveM >> j) & 1ULL)) continue;   // dead frontier: no work at all

        // ISSUE: 16 dual-row loads (lanes<32: rows 0..15, lanes>=32: rows 16..31)
        const unsigned ms   = mask_s[j];        // wave-uniform LDS broadcast
        const int selfnode  = nodes_s[j];
        const int* idr      = &idx_s[j * DEG];
        float2 V[16];
        #pragma unroll
        for (int n = 0; n < 16; ++n) {
            const int rid = idr[n + hsel];                  // 2-addr LDS broadcast
            V[n] = x2[rid * (F_IN / 2) + l32];              // 2 rows per instruction
        }
        float2 sV = x2[selfnode * (F_IN / 2) + l32];

        // OVERLAP: previous j's GEMM1 runs while the 17 loads are in flight
        if (jprev >= 0) do_gemm1();

        // CONSUME: masked accumulate (half-rows per lane half), fold, mean
        const unsigned msl = ms >> hsel;        // lanes>=32 see bits 16..31 at 0..15
        float ax = 0.f, ay = 0.f;
        #pragma unroll
        for (int n = 0; n < 16; ++n) {
            const bool k = (msl >> n) & 1u;
            ax += k ? V[n].x : 0.f;
            ay += k ? V[n].y : 0.f;
        }
        ax += __shfl_xor(ax, 32);               // fold the two row-halves
        ay += __shfl_xor(ay, 32);
        ax += sV.x; ay += sV.y;                 // self loop (added once)
        const float rc = __builtin_amdgcn_rcpf((float)(__popc(ms) + 1));
        if (lane < 32)
            *(float2*)&meanw[wid * F_IN + 2 * l32] = make_float2(ax * rc, ay * rc);
        jprev = j;
    }
    if (jprev >= 0) do_gemm1();                 // drain the pipeline

    // ---- cross-wave reduction + GEMM2 (red/aggm overlay W0s after barrier) ----
    __syncthreads();
    float* red  = smem;                         // [NW*F_H]
    float* aggm = smem + NW * F_H;              // [F_H]
    red[wid * F_H + 2 * lane]     = a1x;
    red[wid * F_H + 2 * lane + 1] = a1y;
    __syncthreads();

    if (wid == 0) {
        const float cnt1 = (float)__popcll(liveM);
        float sx = 0.f, sy = 0.f;
        #pragma unroll
        for (int w = 0; w < NW; ++w) {
            sx += red[w * F_H + 2 * lane];
            sy += red[w * F_H + 2 * lane + 1];
        }
        aggm[2 * lane]     = sx / cnt1;
        aggm[2 * lane + 1] = sy / cnt1;
        // same-wave LDS write->read: in-order

        float o = b1[lane];
        #pragma unroll
        for (int k4 = 0; k4 < F_H / 4; ++k4) {
            const float4 a4 = *(const float4*)&aggm[4 * k4];
            o += a4.x * W1[(4 * k4 + 0) * F_OUT + lane];
            o += a4.y * W1[(4 * k4 + 1) * F_OUT + lane];
            o += a4.z * W1[(4 * k4 + 2) * F_OUT + lane];
            o += a4.w * W1[(4 * k4 + 3) * F_OUT + lane];
        }
        out[b * F_OUT + lane] = fmaxf(o, 0.f);
    }
}

extern "C" void kernel_launch(void* const* d_in, const int* in_sizes, int n_in,
                              void* d_out, int out_size, void* d_ws, size_t ws_size,
                              hipStream_t stream)
{
    const float* x     = (const float*)d_in[0];
    const float* times = (const float*)d_in[1];
    const float* ts    = (const float*)d_in[2];
    const float* W0    = (const float*)d_in[3];
    const float* b0    = (const float*)d_in[4];
    const float* W1    = (const float*)d_in[5];
    const float* b1    = (const float*)d_in[6];
    const int*   batch = (const int*)d_in[7];
    const int*   idx   = (const int*)d_in[8];
    float*       out   = (float*)d_out;

    const int B = in_sizes[1];   // 2048 queries
    flowgnn_kernel<<<B, BLOCK, 0, stream>>>(x, times, ts, W0, b0, W1, b1, batch, idx, out);
}